// Round 12
// baseline (175.757 us; speedup 1.0000x reference)
//
#include <hip/hip_runtime.h>

#define NSEQ 2048
#define DH 64
// SCALE * log2(e): softmax tracked in log2 domain (exp -> bare v_exp_f32)
#define QSCALE (0.125f * 1.44269504088896340736f)
#define DEFER_THR 11.5415603f   // 8 * log2(e)
#define QBLK 256
#define KVBLK 128
#define NTILE (NSEQ / KVBLK)    // 16
#define KP 72   // Kt row pitch (144B): conflict-minimal b128 reads, 2-way writes

typedef _Float16 f16x8 __attribute__((ext_vector_type(8)));
typedef _Float16 f16x4 __attribute__((ext_vector_type(4)));
typedef __fp16 fp16x2 __attribute__((ext_vector_type(2)));
typedef float f32x4 __attribute__((ext_vector_type(4)));
typedef unsigned u32x2 __attribute__((ext_vector_type(2)));

// RAW v_exp_f32 (2^x; flush-to-zero for x<-126 is semantically fine here).
#if defined(__has_builtin) && __has_builtin(__builtin_amdgcn_exp2f)
#define EXP2R(x) __builtin_amdgcn_exp2f(x)
#else
static __device__ __forceinline__ float EXP2R(float x) {
    float r; asm("v_exp_f32 %0, %1" : "=v"(r) : "v"(x)); return r;
}
#endif

union TrP { f16x4 h[2]; f16x8 v8; };

// tr-read: per-lane addr = 128B-aligned subtile base + l15*8
#define TRRD(dst, bb, lit) \
    asm volatile("ds_read_b64_tr_b16 %0, %1 offset:" lit : "=v"(dst) : "v"(bb))

// float4 -> f16x4 via packed cvt
#define CVT4(dst, f4) do { \
        union { fp16x2 f2[2]; f16x4 h4; } _u; \
        _u.f2[0] = __builtin_amdgcn_cvt_pkrtz((f4).x, (f4).y); \
        _u.f2[1] = __builtin_amdgcn_cvt_pkrtz((f4).z, (f4).w); \
        (dst) = _u.h4; } while (0)

__global__ __launch_bounds__(512, 4)
void fa_fwd(const float* __restrict__ Qg, const float* __restrict__ Kg,
            const float* __restrict__ Vg, float* __restrict__ Og)
{
    __shared__ _Float16 Kt[2][KVBLK * KP];   // 36864 B
    __shared__ _Float16 Vt[2][KVBLK * DH];   // 32768 B, subtiled [kv/4][d/16][4][16]

    const int tid  = threadIdx.x;
    const int lane = tid & 63;
    const int wv   = tid >> 6;
    const int l15  = lane & 15;
    const int g    = lane >> 4;

    // XCD-aware swizzle: 512 blocks / 8 XCDs
    const int id  = blockIdx.x;
    const int w   = (id & 7) * 64 + (id >> 3);
    const int bh  = w >> 3;
    const int qb0 = (w & 7) * QBLK;
    const size_t base = (size_t)bh * NSEQ * DH;

    f16x8 qf[2][2];
#pragma unroll
    for (int u = 0; u < 2; ++u) {
        const float* qp = Qg + base + (size_t)(qb0 + wv * 32 + u * 16 + l15) * DH;
#pragma unroll
        for (int ks = 0; ks < 2; ++ks)
#pragma unroll
            for (int j = 0; j < 8; ++j)
                qf[u][ks][j] = (_Float16)(qp[32 * ks + 8 * g + j] * QSCALE);
    }

    f32x4 acc[2][4];
#pragma unroll
    for (int u = 0; u < 2; ++u)
#pragma unroll
        for (int nt = 0; nt < 4; ++nt)
            acc[u][nt] = (f32x4){0.f, 0.f, 0.f, 0.f};
    float m_run[2] = {-INFINITY, -INFINITY};
    float l_run[2] = {0.f, 0.f};   // per-lane PARTIAL (this lane's kv slots only)

    // staging map (conflict-free Vt writes), now covering 128 kv rows:
    // loads A,B: kv = 4*(grp>>1) + (l15>>2); loads C,D: kv+64
    const int grp = tid >> 4;
    const int kb4 = grp >> 1;
    const int dhh = (grp & 1) * 32;
    const int kva = kb4 * 4 + (l15 >> 2);
    const int d0a = dhh + (l15 & 3) * 4;
    const int d0b = d0a + 16;
    const float* Kbp = Kg + base;
    const float* Vbp = Vg + base;
    const int offA = kva * DH + d0a;
    const int offB = kva * DH + d0b;
    const int offC = offA + 64 * DH;
    const int offD = offB + 64 * DH;
    const int vta = ((kva >> 2) * 4 + (d0a >> 4)) * 64 + (kva & 3) * 16 + (d0a & 15);
    const int vtb = ((kva >> 2) * 4 + (d0b >> 4)) * 64 + (kva & 3) * 16 + (d0b & 15);
    const int vtc = vta + 4096;   // kv+64 -> +16 kv4-blocks * 4 subtiles * 64 f16
    const int vtd = vtb + 4096;
    const int kta = kva * KP + d0a;
    const int ktb = kva * KP + d0b;
    const int ktc = kta + 64 * KP;
    const int ktd = ktb + 64 * KP;

    float4 kra, krb, krc, krd, vra, vrb, vrc, vrd;
#define STAGE_LOAD(p_) do { \
        const float* kp_ = Kbp + (p_); const float* vp_ = Vbp + (p_); \
        kra = *(const float4*)(kp_ + offA); krb = *(const float4*)(kp_ + offB); \
        krc = *(const float4*)(kp_ + offC); krd = *(const float4*)(kp_ + offD); \
        vra = *(const float4*)(vp_ + offA); vrb = *(const float4*)(vp_ + offB); \
        vrc = *(const float4*)(vp_ + offC); vrd = *(const float4*)(vp_ + offD); \
    } while (0)

#define STAGE_WRITE(bb) do { \
        f16x4 h; \
        CVT4(h, kra); *(f16x4*)&Kt[bb][kta] = h; \
        CVT4(h, krb); *(f16x4*)&Kt[bb][ktb] = h; \
        CVT4(h, krc); *(f16x4*)&Kt[bb][ktc] = h; \
        CVT4(h, krd); *(f16x4*)&Kt[bb][ktd] = h; \
        CVT4(h, vra); *(f16x4*)&Vt[bb][vta] = h; \
        CVT4(h, vrb); *(f16x4*)&Vt[bb][vtb] = h; \
        CVT4(h, vrc); *(f16x4*)&Vt[bb][vtc] = h; \
        CVT4(h, vrd); *(f16x4*)&Vt[bb][vtd] = h; \
    } while (0)

    STAGE_LOAD(0);
    STAGE_WRITE(0);
    __syncthreads();

    const unsigned vtrb = (unsigned)(size_t)(&Vt[0][0]) + (unsigned)(g * 1024 + l15 * 8);

    for (int t = 0; t < NTILE; ++t) {
        const int c = t & 1;

        if (t + 1 < NTILE)
            STAGE_LOAD((size_t)(t + 1) * KVBLK * DH);

        const unsigned vbuf = vtrb + (unsigned)(c * 16384);

#pragma unroll
        for (int hf = 0; hf < 2; ++hf) {
            const int krow0 = 64 * hf;
            // tr bases: subtile kv4 = 16hf + 8ks + 2g + h2, each 512B/kv4
            const unsigned vb0 = vbuf + (unsigned)(hf * 8192);
            const unsigned b00 = vb0;
            const unsigned b01 = vb0 + 512u;
            const unsigned b10 = vb0 + 4096u;
            const unsigned b11 = vb0 + 4608u;

            // ---- QK^T both u ----
            f32x4 s[2][4];
            __builtin_amdgcn_s_setprio(1);
#pragma unroll
            for (int mt = 0; mt < 4; ++mt) {
                const int row = (krow0 + l15 + 16 * mt) * KP;
                const f16x8 k0 = *(const f16x8*)&Kt[c][row + 8 * g];
                const f16x8 k1 = *(const f16x8*)&Kt[c][row + 32 + 8 * g];
                s[0][mt] = __builtin_amdgcn_mfma_f32_16x16x32_f16(k0, qf[0][0],
                               (f32x4){0.f, 0.f, 0.f, 0.f}, 0, 0, 0);
                s[0][mt] = __builtin_amdgcn_mfma_f32_16x16x32_f16(k1, qf[0][1], s[0][mt], 0, 0, 0);
                s[1][mt] = __builtin_amdgcn_mfma_f32_16x16x32_f16(k0, qf[1][0],
                               (f32x4){0.f, 0.f, 0.f, 0.f}, 0, 0, 0);
                s[1][mt] = __builtin_amdgcn_mfma_f32_16x16x32_f16(k1, qf[1][1], s[1][mt], 0, 0, 0);
            }
            __builtin_amdgcn_s_setprio(0);

            // ---- softmax both u -> packed P words ----
            unsigned W[2][4][2];
#pragma unroll
            for (int u = 0; u < 2; ++u) {
                float m0 = fmaxf(fmaxf(s[u][0][0], s[u][0][1]), s[u][0][2]);
                float m1 = fmaxf(fmaxf(s[u][0][3], s[u][1][0]), s[u][1][1]);
                float m2 = fmaxf(fmaxf(s[u][1][2], s[u][1][3]), s[u][2][0]);
                float m3 = fmaxf(fmaxf(s[u][2][1], s[u][2][2]), s[u][2][3]);
                float m4 = fmaxf(fmaxf(s[u][3][0], s[u][3][1]), s[u][3][2]);
                float tmax = fmaxf(fmaxf(m0, m1), fmaxf(fmaxf(m2, m3), fmaxf(m4, s[u][3][3])));
                tmax = fmaxf(tmax, __shfl_xor(tmax, 16));
                tmax = fmaxf(tmax, __shfl_xor(tmax, 32));

                if (!__all(tmax <= m_run[u] + DEFER_THR)) {
                    const float m_new = fmaxf(m_run[u], tmax);
                    const float fac = EXP2R(m_run[u] - m_new);   // row-uniform
                    l_run[u] *= fac;
                    m_run[u] = m_new;
#pragma unroll
                    for (int r = 0; r < 4; ++r) {
                        const float fr = __shfl(fac, 4 * g + r);
#pragma unroll
                        for (int nt = 0; nt < 4; ++nt) acc[u][nt][r] *= fr;
                    }
                }

                float psum = 0.f;
#pragma unroll
                for (int mt = 0; mt < 4; ++mt) {
                    float p0 = EXP2R(s[u][mt][0] - m_run[u]);
                    float p1 = EXP2R(s[u][mt][1] - m_run[u]);
                    float p2 = EXP2R(s[u][mt][2] - m_run[u]);
                    float p3 = EXP2R(s[u][mt][3] - m_run[u]);
                    psum += (p0 + p1) + (p2 + p3);
                    union { fp16x2 f2; unsigned w; } u0, u1;
                    u0.f2 = __builtin_amdgcn_cvt_pkrtz(p0, p1);
                    u1.f2 = __builtin_amdgcn_cvt_pkrtz(p2, p3);
                    W[u][mt][0] = u0.w;
                    W[u][mt][1] = u1.w;
                }
                l_run[u] += psum;   // per-lane partial; reduced in epilogue
            }

            // ---- PV: one tr-read set per ks, shared by both u ----
#pragma unroll
            for (int ks = 0; ks < 2; ++ks) {
                TrP tp[4];
                const unsigned bh0 = ks ? b10 : b00;
                const unsigned bh1 = ks ? b11 : b01;
                TRRD(tp[0].h[0], bh0, "0");   TRRD(tp[0].h[1], bh1, "0");
                TRRD(tp[1].h[0], bh0, "128"); TRRD(tp[1].h[1], bh1, "128");
                TRRD(tp[2].h[0], bh0, "256"); TRRD(tp[2].h[1], bh1, "256");
                TRRD(tp[3].h[0], bh0, "384"); TRRD(tp[3].h[1], bh1, "384");
                asm volatile("s_waitcnt lgkmcnt(0)" ::: "memory");
                __builtin_amdgcn_sched_barrier(0);

#pragma unroll
                for (int u = 0; u < 2; ++u) {
                    unsigned Ta[4];
#pragma unroll
                    for (int h = 0; h < 2; ++h) {
                        u32x2 r1 = __builtin_amdgcn_permlane32_swap(W[u][2 * ks][h], W[u][2 * ks + 1][h], false, false);
                        u32x2 r2 = __builtin_amdgcn_permlane16_swap(r1[0], r1[1], false, false);
                        Ta[h]     = r2[0];
                        Ta[2 + h] = r2[1];
                    }
                    union { unsigned w[4]; f16x8 v; } pau;
                    pau.w[0] = Ta[0]; pau.w[1] = Ta[1];
                    pau.w[2] = Ta[2]; pau.w[3] = Ta[3];

                    __builtin_amdgcn_s_setprio(1);
#pragma unroll
                    for (int nt = 0; nt < 4; ++nt)
                        acc[u][nt] = __builtin_amdgcn_mfma_f32_16x16x32_f16(pau.v, tp[nt].v8, acc[u][nt], 0, 0, 0);
                    __builtin_amdgcn_s_setprio(0);
                }
            }
        }

        if (t + 1 < NTILE) {
            STAGE_WRITE(c ^ 1);
            __syncthreads();
        }
    }

    // epilogue: reduce l partials across the 4 groups, then O = acc / l
#pragma unroll
    for (int u = 0; u < 2; ++u) {
        l_run[u] += __shfl_xor(l_run[u], 16);
        l_run[u] += __shfl_xor(l_run[u], 32);
#pragma unroll
        for (int r = 0; r < 4; ++r) {
            const float lr  = __shfl(l_run[u], 4 * g + r);
            const float inv = 1.0f / lr;
            const int row = qb0 + wv * 32 + u * 16 + 4 * g + r;
            float* op = Og + base + (size_t)row * DH;
#pragma unroll
            for (int nt = 0; nt < 4; ++nt)
                op[16 * nt + l15] = acc[u][nt][r] * inv;
        }
    }
}

extern "C" void kernel_launch(void* const* d_in, const int* in_sizes, int n_in,
                              void* d_out, int out_size, void* d_ws, size_t ws_size,
                              hipStream_t stream) {
    const float* Q = (const float*)d_in[0];
    const float* K = (const float*)d_in[1];
    const float* V = (const float*)d_in[2];
    float* O = (float*)d_out;
    fa_fwd<<<dim3(512, 1, 1), dim3(512, 1, 1), 0, stream>>>(Q, K, V, O);
}

// Round 13
// 98.127 us; speedup vs baseline: 1.7911x; 1.7911x over previous
//
#include <hip/hip_runtime.h>

#define NSEQ 2048
#define DH 64
// SCALE * log2(e): softmax tracked in log2 domain (exp -> bare v_exp_f32)
#define QSCALE (0.125f * 1.44269504088896340736f)
#define DEFER_THR 11.5415603f   // 8 * log2(e)
#define QBLK 256
#define KVBLK 128
#define NTILE (NSEQ / KVBLK)    // 16
#define KP 72   // Kt row pitch (144B): conflict-minimal b128 reads, 2-way writes

typedef _Float16 f16x8 __attribute__((ext_vector_type(8)));
typedef _Float16 f16x4 __attribute__((ext_vector_type(4)));
typedef __fp16 fp16x2 __attribute__((ext_vector_type(2)));
typedef float f32x4 __attribute__((ext_vector_type(4)));
typedef unsigned u32x2 __attribute__((ext_vector_type(2)));

// RAW v_exp_f32 (2^x; flush-to-zero for x<-126 is semantically fine here).
#if defined(__has_builtin) && __has_builtin(__builtin_amdgcn_exp2f)
#define EXP2R(x) __builtin_amdgcn_exp2f(x)
#else
static __device__ __forceinline__ float EXP2R(float x) {
    float r; asm("v_exp_f32 %0, %1" : "=v"(r) : "v"(x)); return r;
}
#endif

union TrP { f16x4 h[2]; f16x8 v8; };

// tr-read: per-lane addr = 128B-aligned subtile base + l15*8
#define TRRD(dst, bb, lit) \
    asm volatile("ds_read_b64_tr_b16 %0, %1 offset:" lit : "=v"(dst) : "v"(bb))

// float4 -> f16x4 via packed cvt
#define CVT4(dst, f4) do { \
        union { fp16x2 f2[2]; f16x4 h4; } _u; \
        _u.f2[0] = __builtin_amdgcn_cvt_pkrtz((f4).x, (f4).y); \
        _u.f2[1] = __builtin_amdgcn_cvt_pkrtz((f4).z, (f4).w); \
        (dst) = _u.h4; } while (0)

__global__ __launch_bounds__(512, 4)
void fa_fwd(const float* __restrict__ Qg, const float* __restrict__ Kg,
            const float* __restrict__ Vg, float* __restrict__ Og)
{
    __shared__ _Float16 Kt[2][KVBLK * KP];   // 36864 B
    __shared__ _Float16 Vt[2][KVBLK * DH];   // 32768 B, subtiled [kv/4][d/16][4][16]

    const int tid  = threadIdx.x;
    const int lane = tid & 63;
    const int wv   = tid >> 6;
    const int l15  = lane & 15;
    const int g    = lane >> 4;

    // XCD-aware swizzle: 512 blocks / 8 XCDs
    const int id  = blockIdx.x;
    const int w   = (id & 7) * 64 + (id >> 3);
    const int bh  = w >> 3;
    const int qb0 = (w & 7) * QBLK;
    const size_t base = (size_t)bh * NSEQ * DH;

    f16x8 qf[2][2];
#pragma unroll
    for (int u = 0; u < 2; ++u) {
        const float* qp = Qg + base + (size_t)(qb0 + wv * 32 + u * 16 + l15) * DH;
#pragma unroll
        for (int ks = 0; ks < 2; ++ks)
#pragma unroll
            for (int j = 0; j < 8; ++j)
                qf[u][ks][j] = (_Float16)(qp[32 * ks + 8 * g + j] * QSCALE);
    }

    f32x4 acc[2][4];
#pragma unroll
    for (int u = 0; u < 2; ++u)
#pragma unroll
        for (int nt = 0; nt < 4; ++nt)
            acc[u][nt] = (f32x4){0.f, 0.f, 0.f, 0.f};
    float m_run[2] = {-INFINITY, -INFINITY};
    float l_run[2] = {0.f, 0.f};   // per-lane PARTIAL; reduced in epilogue

    // staging map (conflict-free Vt writes), covering 128 kv rows:
    // loads A,B: kv = 4*(grp>>1) + (l15>>2); loads C,D: kv+64
    const int grp = tid >> 4;
    const int kb4 = grp >> 1;
    const int dhh = (grp & 1) * 32;
    const int kva = kb4 * 4 + (l15 >> 2);
    const int d0a = dhh + (l15 & 3) * 4;
    const int d0b = d0a + 16;
    const float* Kbp = Kg + base;
    const float* Vbp = Vg + base;
    const int offA = kva * DH + d0a;
    const int offB = kva * DH + d0b;
    const int offC = offA + 64 * DH;
    const int offD = offB + 64 * DH;
    const int vta = ((kva >> 2) * 4 + (d0a >> 4)) * 64 + (kva & 3) * 16 + (d0a & 15);
    const int vtb = ((kva >> 2) * 4 + (d0b >> 4)) * 64 + (kva & 3) * 16 + (d0b & 15);
    const int vtc = vta + 4096;   // kv+64 -> +16 kv4-blocks * 4 subtiles * 64 f16
    const int vtd = vtb + 4096;
    const int kta = kva * KP + d0a;
    const int ktb = kva * KP + d0b;
    const int ktc = kta + 64 * KP;
    const int ktd = ktb + 64 * KP;

    // STAGE: load + convert + write in one tight region (short register
    // lifetimes -- round 12's tile-long float4 prefetch spilled at the
    // 64-arch-VGPR budget). VMEM latency is covered by the other block/CU.
#define STAGE(bb, kp_, vp_) do { \
        float4 f0 = *(const float4*)((kp_) + offA); \
        float4 f1 = *(const float4*)((kp_) + offB); \
        float4 f2 = *(const float4*)((kp_) + offC); \
        float4 f3 = *(const float4*)((kp_) + offD); \
        float4 f4v = *(const float4*)((vp_) + offA); \
        float4 f5 = *(const float4*)((vp_) + offB); \
        float4 f6 = *(const float4*)((vp_) + offC); \
        float4 f7 = *(const float4*)((vp_) + offD); \
        f16x4 h; \
        CVT4(h, f0); *(f16x4*)&Kt[bb][kta] = h; \
        CVT4(h, f1); *(f16x4*)&Kt[bb][ktb] = h; \
        CVT4(h, f2); *(f16x4*)&Kt[bb][ktc] = h; \
        CVT4(h, f3); *(f16x4*)&Kt[bb][ktd] = h; \
        CVT4(h, f4v); *(f16x4*)&Vt[bb][vta] = h; \
        CVT4(h, f5); *(f16x4*)&Vt[bb][vtb] = h; \
        CVT4(h, f6); *(f16x4*)&Vt[bb][vtc] = h; \
        CVT4(h, f7); *(f16x4*)&Vt[bb][vtd] = h; \
    } while (0)

    STAGE(0, Kbp, Vbp);
    __syncthreads();

    const float* kpre = Kbp + KVBLK * DH;   // pointer-increment prefetch (SGPR-lean)
    const float* vpre = Vbp + KVBLK * DH;

    const unsigned vtrb = (unsigned)(size_t)(&Vt[0][0]) + (unsigned)(g * 1024 + l15 * 8);

    for (int t = 0; t < NTILE; ++t) {
        const int c = t & 1;
        const unsigned vbuf = vtrb + (unsigned)(c * 16384);

#pragma unroll
        for (int hf = 0; hf < 2; ++hf) {
            const int krow0 = 64 * hf;
            const unsigned vb0 = vbuf + (unsigned)(hf * 8192);
            const unsigned b00 = vb0;
            const unsigned b01 = vb0 + 512u;
            const unsigned b10 = vb0 + 4096u;
            const unsigned b11 = vb0 + 4608u;

            // ---- QK^T both u ----
            f32x4 s[2][4];
            __builtin_amdgcn_s_setprio(1);
#pragma unroll
            for (int mt = 0; mt < 4; ++mt) {
                const int row = (krow0 + l15 + 16 * mt) * KP;
                const f16x8 k0 = *(const f16x8*)&Kt[c][row + 8 * g];
                const f16x8 k1 = *(const f16x8*)&Kt[c][row + 32 + 8 * g];
                s[0][mt] = __builtin_amdgcn_mfma_f32_16x16x32_f16(k0, qf[0][0],
                               (f32x4){0.f, 0.f, 0.f, 0.f}, 0, 0, 0);
                s[0][mt] = __builtin_amdgcn_mfma_f32_16x16x32_f16(k1, qf[0][1], s[0][mt], 0, 0, 0);
                s[1][mt] = __builtin_amdgcn_mfma_f32_16x16x32_f16(k0, qf[1][0],
                               (f32x4){0.f, 0.f, 0.f, 0.f}, 0, 0, 0);
                s[1][mt] = __builtin_amdgcn_mfma_f32_16x16x32_f16(k1, qf[1][1], s[1][mt], 0, 0, 0);
            }
            __builtin_amdgcn_s_setprio(0);

            // ---- softmax both u -> packed P words ----
            unsigned W[2][4][2];
#pragma unroll
            for (int u = 0; u < 2; ++u) {
                float m0 = fmaxf(fmaxf(s[u][0][0], s[u][0][1]), s[u][0][2]);
                float m1 = fmaxf(fmaxf(s[u][0][3], s[u][1][0]), s[u][1][1]);
                float m2 = fmaxf(fmaxf(s[u][1][2], s[u][1][3]), s[u][2][0]);
                float m3 = fmaxf(fmaxf(s[u][2][1], s[u][2][2]), s[u][2][3]);
                float m4 = fmaxf(fmaxf(s[u][3][0], s[u][3][1]), s[u][3][2]);
                float tmax = fmaxf(fmaxf(m0, m1), fmaxf(fmaxf(m2, m3), fmaxf(m4, s[u][3][3])));
                tmax = fmaxf(tmax, __shfl_xor(tmax, 16));
                tmax = fmaxf(tmax, __shfl_xor(tmax, 32));

                if (!__all(tmax <= m_run[u] + DEFER_THR)) {
                    const float m_new = fmaxf(m_run[u], tmax);
                    const float fac = EXP2R(m_run[u] - m_new);   // row-uniform
                    l_run[u] *= fac;
                    m_run[u] = m_new;
#pragma unroll
                    for (int r = 0; r < 4; ++r) {
                        const float fr = __shfl(fac, 4 * g + r);
#pragma unroll
                        for (int nt = 0; nt < 4; ++nt) acc[u][nt][r] *= fr;
                    }
                }

                float psum = 0.f;
#pragma unroll
                for (int mt = 0; mt < 4; ++mt) {
                    float p0 = EXP2R(s[u][mt][0] - m_run[u]);
                    float p1 = EXP2R(s[u][mt][1] - m_run[u]);
                    float p2 = EXP2R(s[u][mt][2] - m_run[u]);
                    float p3 = EXP2R(s[u][mt][3] - m_run[u]);
                    psum += (p0 + p1) + (p2 + p3);
                    union { fp16x2 f2; unsigned w; } u0, u1;
                    u0.f2 = __builtin_amdgcn_cvt_pkrtz(p0, p1);
                    u1.f2 = __builtin_amdgcn_cvt_pkrtz(p2, p3);
                    W[u][mt][0] = u0.w;
                    W[u][mt][1] = u1.w;
                }
                l_run[u] += psum;   // per-lane partial
            }

            // ---- PV: one tr-read set per ks, shared by both u ----
#pragma unroll
            for (int ks = 0; ks < 2; ++ks) {
                TrP tp[4];
                const unsigned bh0 = ks ? b10 : b00;
                const unsigned bh1 = ks ? b11 : b01;
                TRRD(tp[0].h[0], bh0, "0");   TRRD(tp[0].h[1], bh1, "0");
                TRRD(tp[1].h[0], bh0, "128"); TRRD(tp[1].h[1], bh1, "128");
                TRRD(tp[2].h[0], bh0, "256"); TRRD(tp[2].h[1], bh1, "256");
                TRRD(tp[3].h[0], bh0, "384"); TRRD(tp[3].h[1], bh1, "384");
                asm volatile("s_waitcnt lgkmcnt(0)" ::: "memory");
                __builtin_amdgcn_sched_barrier(0);

#pragma unroll
                for (int u = 0; u < 2; ++u) {
                    unsigned Ta[4];
#pragma unroll
                    for (int h = 0; h < 2; ++h) {
                        u32x2 r1 = __builtin_amdgcn_permlane32_swap(W[u][2 * ks][h], W[u][2 * ks + 1][h], false, false);
                        u32x2 r2 = __builtin_amdgcn_permlane16_swap(r1[0], r1[1], false, false);
                        Ta[h]     = r2[0];
                        Ta[2 + h] = r2[1];
                    }
                    union { unsigned w[4]; f16x8 v; } pau;
                    pau.w[0] = Ta[0]; pau.w[1] = Ta[1];
                    pau.w[2] = Ta[2]; pau.w[3] = Ta[3];

                    __builtin_amdgcn_s_setprio(1);
#pragma unroll
                    for (int nt = 0; nt < 4; ++nt)
                        acc[u][nt] = __builtin_amdgcn_mfma_f32_16x16x32_f16(pau.v, tp[nt].v8, acc[u][nt], 0, 0, 0);
                    __builtin_amdgcn_s_setprio(0);
                }
            }
        }

        // stage tile t+1 (load+cvt+write, short-lived regs), single barrier
        if (t + 1 < NTILE) {
            STAGE(c ^ 1, kpre, vpre);
            kpre += KVBLK * DH;
            vpre += KVBLK * DH;
            __syncthreads();
        }
    }

    // epilogue: reduce l partials across the 4 groups, then O = acc / l
#pragma unroll
    for (int u = 0; u < 2; ++u) {
        l_run[u] += __shfl_xor(l_run[u], 16);
        l_run[u] += __shfl_xor(l_run[u], 32);
#pragma unroll
        for (int r = 0; r < 4; ++r) {
            const float lr  = __shfl(l_run[u], 4 * g + r);
            const float inv = 1.0f / lr;
            const int row = qb0 + wv * 32 + u * 16 + 4 * g + r;
            float* op = Og + base + (size_t)row * DH;
#pragma unroll
            for (int nt = 0; nt < 4; ++nt)
                op[16 * nt + l15] = acc[u][nt][r] * inv;
        }
    }
}

extern "C" void kernel_launch(void* const* d_in, const int* in_sizes, int n_in,
                              void* d_out, int out_size, void* d_ws, size_t ws_size,
                              hipStream_t stream) {
    const float* Q = (const float*)d_in[0];
    const float* K = (const float*)d_in[1];
    const float* V = (const float*)d_in[2];
    float* O = (float*)d_out;
    fa_fwd<<<dim3(512, 1, 1), dim3(512, 1, 1), 0, stream>>>(Q, K, V, O);
}

// Round 14
// 95.470 us; speedup vs baseline: 1.8410x; 1.0278x over previous
//
#include <hip/hip_runtime.h>

#define NSEQ 2048
#define DH 64
// SCALE * log2(e): softmax tracked in log2 domain (exp -> bare v_exp_f32)
#define QSCALE (0.125f * 1.44269504088896340736f)
#define DEFER_THR 11.5415603f   // 8 * log2(e)
#define QBLK 256
#define KVBLK 128
#define NTILE (NSEQ / KVBLK)    // 16
#define KP 72   // Kt row pitch (144B): conflict-minimal b128 reads, 2-way writes

typedef _Float16 f16x8 __attribute__((ext_vector_type(8)));
typedef _Float16 f16x4 __attribute__((ext_vector_type(4)));
typedef __fp16 fp16x2 __attribute__((ext_vector_type(2)));
typedef float f32x4 __attribute__((ext_vector_type(4)));
typedef unsigned u32x2 __attribute__((ext_vector_type(2)));

// RAW v_exp_f32 (2^x; flush-to-zero for x<-126 is semantically fine here).
#if defined(__has_builtin) && __has_builtin(__builtin_amdgcn_exp2f)
#define EXP2R(x) __builtin_amdgcn_exp2f(x)
#else
static __device__ __forceinline__ float EXP2R(float x) {
    float r; asm("v_exp_f32 %0, %1" : "=v"(r) : "v"(x)); return r;
}
#endif

union TrP { f16x4 h[2]; f16x8 v8; };

// tr-read: per-lane addr = 128B-aligned subtile base + l15*8
#define TRRD(dst, bb, lit) \
    asm volatile("ds_read_b64_tr_b16 %0, %1 offset:" lit : "=v"(dst) : "v"(bb))

// float4 -> f16x4 via packed cvt
#define CVT4(dst, f4) do { \
        union { fp16x2 f2[2]; f16x4 h4; } _u; \
        _u.f2[0] = __builtin_amdgcn_cvt_pkrtz((f4).x, (f4).y); \
        _u.f2[1] = __builtin_amdgcn_cvt_pkrtz((f4).z, (f4).w); \
        (dst) = _u.h4; } while (0)

__global__ __launch_bounds__(512, 4)
void fa_fwd(const float* __restrict__ Qg, const float* __restrict__ Kg,
            const float* __restrict__ Vg, float* __restrict__ Og)
{
    __shared__ _Float16 Kt[2][KVBLK * KP];   // 36864 B
    __shared__ _Float16 Vt[2][KVBLK * DH];   // 32768 B, subtiled [kv/4][d/16][4][16]

    const int tid  = threadIdx.x;
    const int lane = tid & 63;
    const int wv   = tid >> 6;
    const int l15  = lane & 15;
    const int g    = lane >> 4;

    // XCD-aware swizzle: 512 blocks / 8 XCDs
    const int id  = blockIdx.x;
    const int w   = (id & 7) * 64 + (id >> 3);
    const int bh  = w >> 3;
    const int qb0 = (w & 7) * QBLK;
    const size_t base = (size_t)bh * NSEQ * DH;

    f16x8 qf[2][2];
#pragma unroll
    for (int u = 0; u < 2; ++u) {
        const float* qp = Qg + base + (size_t)(qb0 + wv * 32 + u * 16 + l15) * DH;
#pragma unroll
        for (int ks = 0; ks < 2; ++ks)
#pragma unroll
            for (int j = 0; j < 8; ++j)
                qf[u][ks][j] = (_Float16)(qp[32 * ks + 8 * g + j] * QSCALE);
    }

    f32x4 acc[2][4];
#pragma unroll
    for (int u = 0; u < 2; ++u)
#pragma unroll
        for (int nt = 0; nt < 4; ++nt)
            acc[u][nt] = (f32x4){0.f, 0.f, 0.f, 0.f};
    // m starts at 0 (finite!) so -m can seed the MFMA C operand; defer-max
    // handles any growth. Scores sigma ~1.4 log2-units -> rescale ~never fires.
    float m_run[2] = {0.f, 0.f};
    float l_run[2] = {0.f, 0.f};   // per-lane PARTIAL; reduced in epilogue

    // staging map (conflict-free Vt writes), covering 128 kv rows
    const int grp = tid >> 4;
    const int kb4 = grp >> 1;
    const int dhh = (grp & 1) * 32;
    const int kva = kb4 * 4 + (l15 >> 2);
    const int d0a = dhh + (l15 & 3) * 4;
    const int d0b = d0a + 16;
    const float* Kbp = Kg + base;
    const float* Vbp = Vg + base;
    const int offA = kva * DH + d0a;
    const int offB = kva * DH + d0b;
    const int offC = offA + 64 * DH;
    const int offD = offB + 64 * DH;
    const int vta = ((kva >> 2) * 4 + (d0a >> 4)) * 64 + (kva & 3) * 16 + (d0a & 15);
    const int vtb = ((kva >> 2) * 4 + (d0b >> 4)) * 64 + (kva & 3) * 16 + (d0b & 15);
    const int vtc = vta + 4096;
    const int vtd = vtb + 4096;
    const int kta = kva * KP + d0a;
    const int ktb = kva * KP + d0b;
    const int ktc = kta + 64 * KP;
    const int ktd = ktb + 64 * KP;

    // STAGE: load + convert + write in one tight region (short reg lifetimes)
#define STAGE(bb, kp_, vp_) do { \
        float4 f0 = *(const float4*)((kp_) + offA); \
        float4 f1 = *(const float4*)((kp_) + offB); \
        float4 f2 = *(const float4*)((kp_) + offC); \
        float4 f3 = *(const float4*)((kp_) + offD); \
        float4 f4v = *(const float4*)((vp_) + offA); \
        float4 f5 = *(const float4*)((vp_) + offB); \
        float4 f6 = *(const float4*)((vp_) + offC); \
        float4 f7 = *(const float4*)((vp_) + offD); \
        f16x4 h; \
        CVT4(h, f0); *(f16x4*)&Kt[bb][kta] = h; \
        CVT4(h, f1); *(f16x4*)&Kt[bb][ktb] = h; \
        CVT4(h, f2); *(f16x4*)&Kt[bb][ktc] = h; \
        CVT4(h, f3); *(f16x4*)&Kt[bb][ktd] = h; \
        CVT4(h, f4v); *(f16x4*)&Vt[bb][vta] = h; \
        CVT4(h, f5); *(f16x4*)&Vt[bb][vtb] = h; \
        CVT4(h, f6); *(f16x4*)&Vt[bb][vtc] = h; \
        CVT4(h, f7); *(f16x4*)&Vt[bb][vtd] = h; \
    } while (0)

    STAGE(0, Kbp, Vbp);
    __syncthreads();

    const float* kpre = Kbp + KVBLK * DH;
    const float* vpre = Vbp + KVBLK * DH;

    const unsigned vtrb = (unsigned)(size_t)(&Vt[0][0]) + (unsigned)(g * 1024 + l15 * 8);
    const fp16x2 ones2 = {(__fp16)1.0f, (__fp16)1.0f};

    for (int t = 0; t < NTILE; ++t) {
        const int c = t & 1;
        const unsigned vbuf = vtrb + (unsigned)(c * 16384);

#pragma unroll
        for (int hf = 0; hf < 2; ++hf) {
            const int krow0 = 64 * hf;
            const unsigned vb0 = vbuf + (unsigned)(hf * 8192);
            const unsigned b00 = vb0;
            const unsigned b01 = vb0 + 512u;
            const unsigned b10 = vb0 + 4096u;
            const unsigned b11 = vb0 + 4608u;

            // ---- QK^T both u, C seeded with -m (pre-centered scores) ----
            const float nm0 = -m_run[0], nm1 = -m_run[1];
            const f32x4 ci0 = {nm0, nm0, nm0, nm0};
            const f32x4 ci1 = {nm1, nm1, nm1, nm1};
            f32x4 s[2][4];
            __builtin_amdgcn_s_setprio(1);
#pragma unroll
            for (int mt = 0; mt < 4; ++mt) {
                const int row = (krow0 + l15 + 16 * mt) * KP;
                const f16x8 k0 = *(const f16x8*)&Kt[c][row + 8 * g];
                const f16x8 k1 = *(const f16x8*)&Kt[c][row + 32 + 8 * g];
                s[0][mt] = __builtin_amdgcn_mfma_f32_16x16x32_f16(k0, qf[0][0], ci0, 0, 0, 0);
                s[0][mt] = __builtin_amdgcn_mfma_f32_16x16x32_f16(k1, qf[0][1], s[0][mt], 0, 0, 0);
                s[1][mt] = __builtin_amdgcn_mfma_f32_16x16x32_f16(k0, qf[1][0], ci1, 0, 0, 0);
                s[1][mt] = __builtin_amdgcn_mfma_f32_16x16x32_f16(k1, qf[1][1], s[1][mt], 0, 0, 0);
            }
            __builtin_amdgcn_s_setprio(0);

            // ---- softmax both u -> packed P words ----
            unsigned W[2][4][2];
#pragma unroll
            for (int u = 0; u < 2; ++u) {
                // s is already centered on m_run; tmax is the EXCESS over m_run
                float m0 = fmaxf(fmaxf(s[u][0][0], s[u][0][1]), s[u][0][2]);
                float m1 = fmaxf(fmaxf(s[u][0][3], s[u][1][0]), s[u][1][1]);
                float m2 = fmaxf(fmaxf(s[u][1][2], s[u][1][3]), s[u][2][0]);
                float m3 = fmaxf(fmaxf(s[u][2][1], s[u][2][2]), s[u][2][3]);
                float m4 = fmaxf(fmaxf(s[u][3][0], s[u][3][1]), s[u][3][2]);
                float tmax = fmaxf(fmaxf(m0, m1), fmaxf(fmaxf(m2, m3), fmaxf(m4, s[u][3][3])));
                tmax = fmaxf(tmax, __shfl_xor(tmax, 16));
                tmax = fmaxf(tmax, __shfl_xor(tmax, 32));

                // T13 defer-max: fire only if excess > THR (rare for this data)
                if (!__all(tmax <= DEFER_THR)) {
                    const float dd  = fmaxf(tmax, 0.f);       // per-row shift
                    const float fac = EXP2R(-dd);
                    l_run[u] *= fac;
                    m_run[u] += dd;
#pragma unroll
                    for (int r = 0; r < 4; ++r) {
                        const float fr = __shfl(fac, 4 * g + r);
#pragma unroll
                        for (int nt = 0; nt < 4; ++nt) acc[u][nt][r] *= fr;
                    }
#pragma unroll
                    for (int mt = 0; mt < 4; ++mt)
#pragma unroll
                        for (int r = 0; r < 4; ++r) s[u][mt][r] -= dd;
                }

                float psum = 0.f;
#pragma unroll
                for (int mt = 0; mt < 4; ++mt) {
                    float p0 = EXP2R(s[u][mt][0]);
                    float p1 = EXP2R(s[u][mt][1]);
                    float p2 = EXP2R(s[u][mt][2]);
                    float p3 = EXP2R(s[u][mt][3]);
                    union { fp16x2 f2; unsigned w; } u0, u1;
                    u0.f2 = __builtin_amdgcn_cvt_pkrtz(p0, p1);
                    u1.f2 = __builtin_amdgcn_cvt_pkrtz(p2, p3);
#if defined(__has_builtin) && __has_builtin(__builtin_amdgcn_fdot2)
                    psum = __builtin_amdgcn_fdot2(u0.f2, ones2, psum, false);
                    psum = __builtin_amdgcn_fdot2(u1.f2, ones2, psum, false);
#else
                    psum += (p0 + p1) + (p2 + p3);
#endif
                    W[u][mt][0] = u0.w;
                    W[u][mt][1] = u1.w;
                }
                l_run[u] += psum;   // per-lane partial
            }

            // ---- PV: one tr-read set per ks, shared by both u ----
#pragma unroll
            for (int ks = 0; ks < 2; ++ks) {
                TrP tp[4];
                const unsigned bh0 = ks ? b10 : b00;
                const unsigned bh1 = ks ? b11 : b01;
                TRRD(tp[0].h[0], bh0, "0");   TRRD(tp[0].h[1], bh1, "0");
                TRRD(tp[1].h[0], bh0, "128"); TRRD(tp[1].h[1], bh1, "128");
                TRRD(tp[2].h[0], bh0, "256"); TRRD(tp[2].h[1], bh1, "256");
                TRRD(tp[3].h[0], bh0, "384"); TRRD(tp[3].h[1], bh1, "384");
                asm volatile("s_waitcnt lgkmcnt(0)" ::: "memory");
                __builtin_amdgcn_sched_barrier(0);

#pragma unroll
                for (int u = 0; u < 2; ++u) {
                    unsigned Ta[4];
#pragma unroll
                    for (int h = 0; h < 2; ++h) {
                        u32x2 r1 = __builtin_amdgcn_permlane32_swap(W[u][2 * ks][h], W[u][2 * ks + 1][h], false, false);
                        u32x2 r2 = __builtin_amdgcn_permlane16_swap(r1[0], r1[1], false, false);
                        Ta[h]     = r2[0];
                        Ta[2 + h] = r2[1];
                    }
                    union { unsigned w2[4]; f16x8 v; } pau;
                    pau.w2[0] = Ta[0]; pau.w2[1] = Ta[1];
                    pau.w2[2] = Ta[2]; pau.w2[3] = Ta[3];

                    __builtin_amdgcn_s_setprio(1);
#pragma unroll
                    for (int nt = 0; nt < 4; ++nt)
                        acc[u][nt] = __builtin_amdgcn_mfma_f32_16x16x32_f16(pau.v, tp[nt].v8, acc[u][nt], 0, 0, 0);
                    __builtin_amdgcn_s_setprio(0);
                }
            }
        }

        // stage tile t+1 (load+cvt+write, short-lived regs), single barrier
        if (t + 1 < NTILE) {
            STAGE(c ^ 1, kpre, vpre);
            kpre += KVBLK * DH;
            vpre += KVBLK * DH;
            __syncthreads();
        }
    }

    // epilogue: reduce l partials across the 4 groups, then O = acc / l
#pragma unroll
    for (int u = 0; u < 2; ++u) {
        l_run[u] += __shfl_xor(l_run[u], 16);
        l_run[u] += __shfl_xor(l_run[u], 32);
#pragma unroll
        for (int r = 0; r < 4; ++r) {
            const float lr  = __shfl(l_run[u], 4 * g + r);
            const float inv = 1.0f / lr;
            const int row = qb0 + wv * 32 + u * 16 + 4 * g + r;
            float* op = Og + base + (size_t)row * DH;
#pragma unroll
            for (int nt = 0; nt < 4; ++nt)
                op[16 * nt + l15] = acc[u][nt][r] * inv;
        }
    }
}

extern "C" void kernel_launch(void* const* d_in, const int* in_sizes, int n_in,
                              void* d_out, int out_size, void* d_ws, size_t ws_size,
                              hipStream_t stream) {
    const float* Q = (const float*)d_in[0];
    const float* K = (const float*)d_in[1];
    const float* V = (const float*)d_in[2];
    float* O = (float*)d_out;
    fa_fwd<<<dim3(512, 1, 1), dim3(512, 1, 1), 0, stream>>>(Q, K, V, O);
}